// Round 9
// baseline (304.045 us; speedup 1.0000x reference)
//
#include <hip/hip_runtime.h>
#include <hip/hip_bf16.h>
#include <float.h>

// Problem constants: S=8192 tokens, E=64 experts, C=256 capacity
constexpr int S = 8192;
constexpr int E = 64;
constexpr int C = 256;
constexpr int EC = E * C;                    // 16384 floats per token region
constexpr int MEGA_BLOCKS = 2048;            // 4 waves each; 1 token per wave
constexpr unsigned THREADS = 256u;
constexpr unsigned TOTAL_THR = MEGA_BLOCKS * THREADS;   // 524288
constexpr unsigned N4 = 33554432u;           // aligned float4s covering floats [0, 134217728)
constexpr int FILL_ITERS = N4 / TOTAL_THR;   // 64, exact
// ws layout: [0, S) float4 token records | then MEGA_BLOCKS*128 floats partials
constexpr size_t WS_PARTIALS_OFF = (size_t)S * 4;   // in floats

typedef float f32x4 __attribute__((ext_vector_type(4)));

// ---------------------------------------------------------------------------
// Mega-kernel: EVERY block does (1) precompute for 4 tokens (one per wave):
// softmax + top-2 -> 16B rec/token + per-block me/ce partials (~2us grid-wide,
// fully parallel), then (2) joins a grid-stride fill of the 537MB output:
// 64 plain float4 zero-stores per thread at 8MB stride — globally contiguous
// per iteration (rocclr fillBufferAligned shape: sliding ~8MB window keeps
// DRAM pages/channels uniformly loaded). No NT flag, no role segregation.
// ---------------------------------------------------------------------------
__global__ __launch_bounds__(256) void mega_kernel(
        const float* __restrict__ logits,
        const float* __restrict__ mask1,
        const float* __restrict__ mask2,
        const float* __restrict__ loc1,
        const float* __restrict__ loc2,
        float4* __restrict__ recs,
        float* __restrict__ ws_partials,
        float* __restrict__ out) {
    __shared__ float me_s[4][64];
    __shared__ float ce_s[4][64];

    const int lane = threadIdx.x & 63;
    const int wave = threadIdx.x >> 6;
    const int s    = blockIdx.x * 4 + wave;      // one token per wave, covers [0, 8192)

    // ---- precompute (R2 math, proven absmax=0) ----
    const float x   = logits[(size_t)s * E + lane];
    const float m1v = mask1[(size_t)s * E + lane];
    const float m2v = mask2[(size_t)s * E + lane];
    const float4 l1v = *reinterpret_cast<const float4*>(loc1 + (size_t)s * C + lane * 4);
    const float4 l2v = *reinterpret_cast<const float4*>(loc2 + (size_t)s * C + lane * 4);

    float mx = x;
    #pragma unroll
    for (int off = 32; off > 0; off >>= 1) mx = fmaxf(mx, __shfl_xor(mx, off));
    const float ex = __expf(x - mx);
    float sum = ex;
    #pragma unroll
    for (int off = 32; off > 0; off >>= 1) sum += __shfl_xor(sum, off);
    const float g = ex / sum;

    const int e1 = __ffsll(__ballot(m1v > 0.5f)) - 1;
    const int e2 = __ffsll(__ballot(m2v > 0.5f)) - 1;
    const float g1 = __shfl(g, e1);
    const float g2 = __shfl(g, e2);

    const int bm1 = (l1v.x > 0.5f ? 1 : 0) | (l1v.y > 0.5f ? 2 : 0) |
                    (l1v.z > 0.5f ? 4 : 0) | (l1v.w > 0.5f ? 8 : 0);
    const int bm2 = (l2v.x > 0.5f ? 1 : 0) | (l2v.y > 0.5f ? 2 : 0) |
                    (l2v.z > 0.5f ? 4 : 0) | (l2v.w > 0.5f ? 8 : 0);
    const int L1 = __ffsll(__ballot(bm1 != 0)) - 1;
    const int L2 = __ffsll(__ballot(bm2 != 0)) - 1;
    const int c1 = L1 * 4 + (__ffs(__shfl(bm1, L1)) - 1);
    const int c2 = L2 * 4 + (__ffs(__shfl(bm2, L2)) - 1);

    if (lane == 0) {
        const float denom = fmaxf(g1 + g2, FLT_EPSILON);
        float4 rec;
        rec.x = g1 / denom;
        rec.y = g2 / denom;
        rec.z = __int_as_float(e1 * C + c1);
        rec.w = __int_as_float(e2 * C + c2);
        recs[s] = rec;
    }

    me_s[wave][lane] = g;      // per-wave single-token contribution
    ce_s[wave][lane] = m1v;
    __syncthreads();
    if (threadIdx.x < 64) {
        const float me_b = me_s[0][lane] + me_s[1][lane] + me_s[2][lane] + me_s[3][lane];
        const float ce_b = ce_s[0][lane] + ce_s[1][lane] + ce_s[2][lane] + ce_s[3][lane];
        ws_partials[(size_t)blockIdx.x * 128 + lane]      = me_b;
        ws_partials[(size_t)blockIdx.x * 128 + 64 + lane] = ce_b;
    }

    // ---- grid-stride fill: 64 plain float4 stores, 8MB stride ----
    f32x4* __restrict__ p = reinterpret_cast<f32x4*>(out);
    const unsigned gtid = blockIdx.x * THREADS + threadIdx.x;
    const f32x4 z = {0.f, 0.f, 0.f, 0.f};
    #pragma unroll 8
    for (int it = 0; it < FILL_ITERS; ++it)
        p[(size_t)gtid + (size_t)it * TOTAL_THR] = z;
    if (gtid == 0) out[(size_t)S * EC] = 0.f;   // tail scalar, float index 134217728
}

// ---------------------------------------------------------------------------
// Finalize: blocks 0..31: one thread per token scatters the two hot dwords
// (coalesced float4 rec loads). Block 32: l_aux reduce -> out[0].
// ---------------------------------------------------------------------------
__global__ __launch_bounds__(256) void finalize_kernel(
        const float4* __restrict__ recs,
        const float* __restrict__ ws_partials,
        float* __restrict__ out) {
    if (blockIdx.x < 32) {
        const int t = blockIdx.x * 256 + threadIdx.x;   // token id, [0, 8192)
        const float4 rec = recs[t];
        float* __restrict__ base = out + 1 + (size_t)t * EC;
        base[__float_as_int(rec.z)] = rec.x;
        base[__float_as_int(rec.w)] = rec.y;
    } else {
        __shared__ float mes[4][64];
        __shared__ float ces[4][64];
        const int e = threadIdx.x & 63;
        const int q = threadIdx.x >> 6;
        float me = 0.f, ce = 0.f;
        for (int b = q; b < MEGA_BLOCKS; b += 4) {
            me += ws_partials[(size_t)b * 128 + e];
            ce += ws_partials[(size_t)b * 128 + 64 + e];
        }
        mes[q][e] = me;
        ces[q][e] = ce;
        __syncthreads();
        if (threadIdx.x < 64) {
            const float m = mes[0][e] + mes[1][e] + mes[2][e] + mes[3][e];
            const float c = ces[0][e] + ces[1][e] + ces[2][e] + ces[3][e];
            float prod = m * c;
            #pragma unroll
            for (int off = 32; off > 0; off >>= 1) prod += __shfl_xor(prod, off);
            if (e == 0) out[0] = prod * (float)E / ((float)S * (float)S);
        }
    }
}

extern "C" void kernel_launch(void* const* d_in, const int* in_sizes, int n_in,
                              void* d_out, int out_size, void* d_ws, size_t ws_size,
                              hipStream_t stream) {
    const float* logits = (const float*)d_in[0];
    const float* mask1  = (const float*)d_in[1];
    const float* mask2  = (const float*)d_in[2];
    const float* loc1   = (const float*)d_in[3];
    const float* loc2   = (const float*)d_in[4];
    float* out = (float*)d_out;
    float* ws  = (float*)d_ws;

    float4* recs        = (float4*)ws;              // S * 16 B
    float*  ws_partials = ws + WS_PARTIALS_OFF;     // MEGA_BLOCKS * 128 floats

    // 1) fused: every block precomputes 4 tokens, then grid-stride fills 537MB
    mega_kernel<<<MEGA_BLOCKS, THREADS, 0, stream>>>(
        logits, mask1, mask2, loc1, loc2, recs, ws_partials, out);

    // 2) scatter 16K hot dwords + l_aux -> out[0]
    finalize_kernel<<<33, 256, 0, stream>>>(recs, ws_partials, out);
}